// Round 1
// 154.827 us; speedup vs baseline: 1.0036x; 1.0036x over previous
//
#include <hip/hip_runtime.h>

// x: (32, 3, 512, 512) fp32, channel plane stride HW = 512*512.
// out: (32, 1, 512, 512) fp32.
// Memory-bound elementwise. Irreducible traffic = 100.7 MB read + 33.6 MB write
// = 134.2 MB -> ~20 us floor at the observed 6.7 TB/s achievable BW.
// 1 thread = 8 pixels (2x float4 per channel), coalesced, nontemporal.

#define HW    262144          // 512*512
#define NPIX  8388608         // 32*HW (output elements)

typedef float f4 __attribute__((ext_vector_type(4)));

__device__ __forceinline__ float hue_px(float r, float g, float b,
                                        float w6, float bb) {
    float cmax  = fmaxf(r, fmaxf(g, b));
    float cmin  = fminf(r, fminf(g, b));
    float delta = cmax - cmin;

    // Raw v_rcp_f32 (~1 ulp). delta==0 -> inv=+inf -> t* = NaN, but those
    // lanes are forced to hue=0 by the final select, matching the reference.
    // Avoids the ~10-op IEEE div sequence AND the safe_delta cndmask.
    float inv = __builtin_amdgcn_rcpf(delta);

    // Sign of t0 == sign of (g-b) exactly (inv > 0), so the mod-wrap branch
    // decision is bit-identical to exact division.
    float t0 = (g - b) * inv;
    t0 = (t0 < 0.0f) ? (t0 + 6.0f) : t0;          // mod((g-b)/d, 6), t0 in [-1,1]
    float t1 = fmaf(b - r, inv, 2.0f);
    float t2 = fmaf(r - g, inv, 4.0f);

    // argmax first-occurrence: r, then g, then b.
    float hue = (r == cmax) ? t0 : ((g == cmax) ? t1 : t2);
    hue = (delta == 0.0f) ? 0.0f : hue;

    return fmaf(hue, w6, bb);                      // out = (hue/6)*W + b
}

__global__ __launch_bounds__(256) void HBEMD_F_67156108640795_kernel(
    const float* __restrict__ x,
    const float* __restrict__ Wp,
    const float* __restrict__ Bp,
    float* __restrict__ out)
{
    int v = blockIdx.x * blockDim.x + threadIdx.x;   // 8-pixel group index
    int o = v << 3;                                  // pixel index
    if (o >= NPIX) return;

    int n = o >> 18;                                 // o / HW
    int p = o & (HW - 1);                            // o % HW (HW multiple of 8)
    const float* base = x + (size_t)n * (3 * HW) + p;

    // Read-once data: nontemporal to keep L2/L3 from caching dead lines.
    f4 r0 = __builtin_nontemporal_load((const f4*)(base));
    f4 r1 = __builtin_nontemporal_load((const f4*)(base + 4));
    f4 g0 = __builtin_nontemporal_load((const f4*)(base + HW));
    f4 g1 = __builtin_nontemporal_load((const f4*)(base + HW + 4));
    f4 b0 = __builtin_nontemporal_load((const f4*)(base + 2 * HW));
    f4 b1 = __builtin_nontemporal_load((const f4*)(base + 2 * HW + 4));

    float w6 = Wp[0] * 0.16666667f;                  // fold /6 into W
    float bb = Bp[0];

    f4 o0, o1;
#pragma unroll
    for (int k = 0; k < 4; ++k) {
        o0[k] = hue_px(r0[k], g0[k], b0[k], w6, bb);
        o1[k] = hue_px(r1[k], g1[k], b1[k], w6, bb);
    }

    __builtin_nontemporal_store(o0, (f4*)(out + o));
    __builtin_nontemporal_store(o1, (f4*)(out + o + 4));
}

extern "C" void kernel_launch(void* const* d_in, const int* in_sizes, int n_in,
                              void* d_out, int out_size, void* d_ws, size_t ws_size,
                              hipStream_t stream) {
    const float* x  = (const float*)d_in[0];
    const float* W  = (const float*)d_in[1];
    const float* b  = (const float*)d_in[2];
    float* out = (float*)d_out;

    const int threads = 256;
    const int ngrp = NPIX / 8;                 // 1,048,576 8-pixel groups
    const int blocks = ngrp / threads;         // 4096 exactly
    HBEMD_F_67156108640795_kernel<<<blocks, threads, 0, stream>>>(x, W, b, out);
}